// Round 7
// baseline (304.237 us; speedup 1.0000x reference)
//
#include <hip/hip_runtime.h>
#include <stdint.h>

// occupancy_generation (DeepMapping2D):
//   out[b, j] = 1.0 if j < min(M_b, 5120) else 0.0
//   M_b = #bins with count >= 53  (count/262144 > 0.0002 <=> count >= 53)
//   histogram over idx = rn(1000x)*1024 + rn(1000z), idx < 2^20
// Min-subtraction in the reference is a pure index translation -> M_b invariant.
//
// R1: scattered global atomics = 512 MB fabric RMW (646 us).
// R2/R3: bucket-sort by region (idx>>14) + u16-packed LDS hist (221 us).
// R4 FAILED: per-block __threadfence ticket = XCD L2 flush storm (+90 us).
// R5/R6: one-pass staging variants all neutral (219-221 us) -> pipeline is a
//     stable ~93 us + ~125 us harness resets; internals varied so far don't
//     matter. Per-kernel durations invisible (top-5 saturated by 78-us fills).
// R7 DIAGNOSTIC: add tripled copies bucketize_kernel3 / region_hist_kernel3
//     (identical structure, 3 reps into scratch) so each exceeds the 78-us
//     top-5 bar and exposes FETCH/WRITE/VALUBusy/Occupancy for the real work.
//     Intentionally slower in total; base pipeline & output unchanged.

static constexpr int kB        = 64;
static constexpr int kN        = 262144;    // points per cloud
static constexpr int kTopK     = 5120;
static constexpr int kRegions  = 64;        // idx>>14 == xi>>4; xi<=1000 -> region<=62
static constexpr int kSlots    = 128;       // per-(block,region) slice; mean 65.5, ~+8 sigma
static constexpr int kStride   = 136;       // staging stride in u16 (272 B, keeps b128 alignment)
static constexpr int kThreads  = 256;
static constexpr int kBlocksPerCloud = 64;  // 4096 points per block
static constexpr unsigned kThresh = 53;
static constexpr int kBucketSlots = kBlocksPerCloud * kSlots;  // 8192 u16 = 16 KB/bucket

// ws layout (nothing pre-zeroed; every consumed byte is written each call):
//   [0      , 16 KB) : parts[4096] u32
//   [256 KB , +16KB) : parts2[4096] u32      (diagnostic sink)
//   [1 MB   , +64MB) : bdata[4096][8192] u16 (0xFFFF = empty)
//   [128 MB , +64MB) : bdata2 (diagnostic sink)

__device__ __forceinline__ void bucketize_body(const float4* __restrict__ pcd4,
                                               uint16_t* __restrict__ bdata,
                                               uint32_t* s_off, uint16_t* s_stage) {
    const int tid   = threadIdx.x;
    const int bid   = blockIdx.x;
    const int cloud = bid >> 6;
    const int batch = bid & 63;
    const size_t f4base = (size_t)cloud * (kN / 2) + (size_t)batch * 2048;

    if (tid < kRegions) s_off[tid] = 0;
    __syncthreads();

#pragma unroll
    for (int j = 0; j < 8; ++j) {
        float4 v = pcd4[f4base + (size_t)j * kThreads + tid];
        // jnp.round == round-half-to-even -> __float2int_rn
        int i0 = __float2int_rn(1000.0f * v.x) * 1024 + __float2int_rn(1000.0f * v.y);
        int i1 = __float2int_rn(1000.0f * v.z) * 1024 + __float2int_rn(1000.0f * v.w);
        uint32_t r0 = (uint32_t)i0 >> 14, b0 = (uint32_t)i0 & 16383u;
        uint32_t r1 = (uint32_t)i1 >> 14, b1 = (uint32_t)i1 & 16383u;
        uint32_t p0 = atomicAdd(&s_off[r0], 1u);
        if (p0 < (uint32_t)kSlots) s_stage[r0 * kStride + p0] = (uint16_t)b0;
        uint32_t p1 = atomicAdd(&s_off[r1], 1u);
        if (p1 < (uint32_t)kSlots) s_stage[r1 * kStride + p1] = (uint16_t)b1;
    }
    __syncthreads();

    // Flush: 1024 uint4 tasks; all 16B-aligned, sentinel 0xFFFF fills in-register.
#pragma unroll
    for (int it = 0; it < 4; ++it) {
        int t = it * kThreads + tid;
        uint32_t r = (uint32_t)t >> 4;
        uint32_t k = (uint32_t)t & 15u;
        uint32_t c = s_off[r];
        if (c > (uint32_t)kSlots) c = (uint32_t)kSlots;
        const uint4 w = *(const uint4*)&s_stage[r * kStride + k * 8u];
        uint32_t slot = k * 8u;
        uint4 o;
        o.x = ((slot + 0 < c) ? (w.x & 0xFFFFu) : 0xFFFFu) |
              (((slot + 1 < c) ? (w.x >> 16)    : 0xFFFFu) << 16);
        o.y = ((slot + 2 < c) ? (w.y & 0xFFFFu) : 0xFFFFu) |
              (((slot + 3 < c) ? (w.y >> 16)    : 0xFFFFu) << 16);
        o.z = ((slot + 4 < c) ? (w.z & 0xFFFFu) : 0xFFFFu) |
              (((slot + 5 < c) ? (w.z >> 16)    : 0xFFFFu) << 16);
        o.w = ((slot + 6 < c) ? (w.w & 0xFFFFu) : 0xFFFFu) |
              (((slot + 7 < c) ? (w.w >> 16)    : 0xFFFFu) << 16);
        uint16_t* dst = bdata + ((size_t)(cloud * kRegions + r) * kBucketSlots
                                 + (uint32_t)batch * kSlots + slot);
        *(uint4*)dst = o;
    }
}

__global__ void __launch_bounds__(kThreads) bucketize_kernel(
    const float4* __restrict__ pcd4, uint16_t* __restrict__ bdata) {
    __shared__ uint32_t s_off[kRegions];
    __shared__ uint16_t s_stage[kRegions * kStride];
    bucketize_body(pcd4, bdata, s_off, s_stage);
}

__global__ void __launch_bounds__(kThreads) bucketize_kernel3(
    const float4* __restrict__ pcd4, uint16_t* __restrict__ bdata2) {
    __shared__ uint32_t s_off[kRegions];
    __shared__ uint16_t s_stage[kRegions * kStride];
    for (int rep = 0; rep < 3; ++rep) {
        bucketize_body(pcd4, bdata2, s_off, s_stage);
        __syncthreads();
    }
}

__device__ __forceinline__ void hist_body(const uint16_t* __restrict__ bdata,
                                          uint32_t* __restrict__ parts,
                                          uint32_t* hist, uint32_t* s_wsum) {
    const int tid = threadIdx.x;
    const int bid = blockIdx.x;  // bucket = cloud*64 + region

    uint4* h4 = (uint4*)hist;
    for (int i = tid; i < 8192 / 4; i += kThreads) h4[i] = make_uint4(0, 0, 0, 0);
    __syncthreads();

    const uint4* src4 = (const uint4*)(bdata + (size_t)bid * kBucketSlots);
#pragma unroll
    for (int it = 0; it < 4; ++it) {          // 1024 uint4 = fixed 16 KB
        uint4 v = src4[it * kThreads + tid];
        uint32_t w;
        w = v.x & 0xFFFFu; if (w < 16384u) atomicAdd(&hist[w >> 1], 1u << (16u * (w & 1u)));
        w = v.x >> 16;     if (w < 16384u) atomicAdd(&hist[w >> 1], 1u << (16u * (w & 1u)));
        w = v.y & 0xFFFFu; if (w < 16384u) atomicAdd(&hist[w >> 1], 1u << (16u * (w & 1u)));
        w = v.y >> 16;     if (w < 16384u) atomicAdd(&hist[w >> 1], 1u << (16u * (w & 1u)));
        w = v.z & 0xFFFFu; if (w < 16384u) atomicAdd(&hist[w >> 1], 1u << (16u * (w & 1u)));
        w = v.z >> 16;     if (w < 16384u) atomicAdd(&hist[w >> 1], 1u << (16u * (w & 1u)));
        w = v.w & 0xFFFFu; if (w < 16384u) atomicAdd(&hist[w >> 1], 1u << (16u * (w & 1u)));
        w = v.w >> 16;     if (w < 16384u) atomicAdd(&hist[w >> 1], 1u << (16u * (w & 1u)));
    }
    __syncthreads();

    uint32_t local = 0;
    for (int i = tid; i < 8192 / 4; i += kThreads) {
        uint4 v = h4[i];
        local += ((v.x & 0xFFFFu) >= kThresh) + ((v.x >> 16) >= kThresh);
        local += ((v.y & 0xFFFFu) >= kThresh) + ((v.y >> 16) >= kThresh);
        local += ((v.z & 0xFFFFu) >= kThresh) + ((v.z >> 16) >= kThresh);
        local += ((v.w & 0xFFFFu) >= kThresh) + ((v.w >> 16) >= kThresh);
    }
#pragma unroll
    for (int d = 32; d; d >>= 1) local += __shfl_down(local, d, 64);
    if ((tid & 63) == 0) s_wsum[tid >> 6] = local;
    __syncthreads();
    if (tid == 0)
        parts[bid] = s_wsum[0] + s_wsum[1] + s_wsum[2] + s_wsum[3];
}

__global__ void __launch_bounds__(kThreads) region_hist_kernel(
    const uint16_t* __restrict__ bdata, uint32_t* __restrict__ parts) {
    __shared__ uint32_t hist[8192];   // u16-packed: 16384 bins, 32 KB
    __shared__ uint32_t s_wsum[kThreads / 64];
    hist_body(bdata, parts, hist, s_wsum);
}

__global__ void __launch_bounds__(kThreads) region_hist_kernel3(
    const uint16_t* __restrict__ bdata2, uint32_t* __restrict__ parts2) {
    __shared__ uint32_t hist[8192];
    __shared__ uint32_t s_wsum[kThreads / 64];
    for (int rep = 0; rep < 3; ++rep) {
        hist_body(bdata2, parts2, hist, s_wsum);
        __syncthreads();
    }
}

__global__ void __launch_bounds__(kThreads) out_kernel(const uint32_t* __restrict__ parts,
                                                       float* __restrict__ out) {
    __shared__ uint32_t s_m;
    const int b = blockIdx.x;  // one block per cloud
    const int tid = threadIdx.x;
    if (tid < 64) {
        uint32_t v = parts[b * kRegions + tid];
#pragma unroll
        for (int d = 32; d; d >>= 1) v += __shfl_down(v, d, 64);
        if (tid == 0) s_m = v;
    }
    __syncthreads();
    const uint32_t m = s_m;
    const uint32_t cut = m < (uint32_t)kTopK ? m : (uint32_t)kTopK;
    float4* row = (float4*)(out + (size_t)b * kTopK);
    for (int i = tid; i < kTopK / 4; i += kThreads) {
        uint32_t j = (uint32_t)i * 4u;
        row[i] = make_float4(j < cut ? 1.0f : 0.0f, j + 1 < cut ? 1.0f : 0.0f,
                             j + 2 < cut ? 1.0f : 0.0f, j + 3 < cut ? 1.0f : 0.0f);
    }
}

extern "C" void kernel_launch(void* const* d_in, const int* in_sizes, int n_in,
                              void* d_out, int out_size, void* d_ws, size_t ws_size,
                              hipStream_t stream) {
    const float4* pcd4 = (const float4*)d_in[0];
    float* out = (float*)d_out;

    uint32_t* parts  = (uint32_t*)d_ws;
    uint32_t* parts2 = (uint32_t*)((char*)d_ws + (256 << 10));
    uint16_t* bdata  = (uint16_t*)((char*)d_ws + (1 << 20));
    uint16_t* bdata2 = (uint16_t*)((char*)d_ws + (128u << 20));

    // --- real pipeline (unchanged from R6) ---
    bucketize_kernel<<<kB * kBlocksPerCloud, kThreads, 0, stream>>>(pcd4, bdata);
    region_hist_kernel<<<kB * kRegions, kThreads, 0, stream>>>(bdata, parts);
    out_kernel<<<kB, kThreads, 0, stream>>>(parts, out);

    // --- diagnostic tripled copies (profiler-visible; output unaffected) ---
    bucketize_kernel3<<<kB * kBlocksPerCloud, kThreads, 0, stream>>>(pcd4, bdata2);
    region_hist_kernel3<<<kB * kRegions, kThreads, 0, stream>>>(bdata2, parts2);
}

// Round 8
// 220.344 us; speedup vs baseline: 1.3807x; 1.3807x over previous
//
#include <hip/hip_runtime.h>
#include <stdint.h>

// occupancy_generation (DeepMapping2D):
//   out[b, j] = 1.0 if j < min(M_b, 5120) else 0.0
//   M_b = #bins with count >= 53  (count/262144 > 0.0002 <=> count >= 53)
//   histogram over idx = rn(1000x)*1024 + rn(1000z), idx < 2^20
// Min-subtraction in the reference is a pure index translation -> M_b invariant.
//
// R1: scattered global atomics = 512 MB fabric RMW (646 us).
// R2/R3: bucket-sort by region (idx>>14) + u16-packed LDS hist (221 us).
// R4 FAILED: per-block __threadfence ticket = XCD L2 flush storm (+90 us).
// R5/R6: staging variants neutral (219-221 us).
// R7 DIAGNOSTIC: tripled-kernel timing attribution ->
//     bucketize+hist = ~28 us total (input-read BW floor ~21 us);
//     harness resets = ~190 us of the 220 (512 MB 0xAA fill at 87% HBM peak
//     + 134 MB input restore, in-graph, irreducible from kernel side).
// R8: clean revert to the R6 pipeline (3 kernels, no memset, no global
//     atomics). Within ~25% of the cold-HBM input-read roofline; total is
//     reset-dominated.

static constexpr int kB        = 64;
static constexpr int kN        = 262144;    // points per cloud
static constexpr int kTopK     = 5120;
static constexpr int kRegions  = 64;        // idx>>14 == xi>>4; xi<=1000 -> region<=62
static constexpr int kSlots    = 128;       // per-(block,region) slice; mean 65.5, ~+8 sigma
static constexpr int kStride   = 136;       // staging stride in u16 (272 B, keeps b128 alignment)
static constexpr int kThreads  = 256;
static constexpr int kBlocksPerCloud = 64;  // 4096 points per block
static constexpr unsigned kThresh = 53;
static constexpr int kBucketSlots = kBlocksPerCloud * kSlots;  // 8192 u16 = 16 KB/bucket

// ws layout (nothing pre-zeroed; every consumed byte is written each call):
//   [0      , 16 KB) : parts[4096] u32  (per (cloud,region) occupied-bin counts)
//   [1 MB   , +64MB) : bdata[4096][8192] u16 (bin-in-region values, 0xFFFF = empty)

__global__ void __launch_bounds__(kThreads) bucketize_kernel(
    const float4* __restrict__ pcd4, uint16_t* __restrict__ bdata) {
    __shared__ uint32_t s_off[kRegions];              // placement cursors
    __shared__ uint16_t s_stage[kRegions * kStride];  // 17 KB

    const int tid   = threadIdx.x;
    const int bid   = blockIdx.x;
    const int cloud = bid >> 6;                       // 64 blocks per cloud
    const int batch = bid & 63;
    const size_t f4base = (size_t)cloud * (kN / 2) + (size_t)batch * 2048;

    if (tid < kRegions) s_off[tid] = 0;
    __syncthreads();

    // Single pass: load -> quantize -> place into per-region staging slice.
#pragma unroll
    for (int j = 0; j < 8; ++j) {
        float4 v = pcd4[f4base + (size_t)j * kThreads + tid];
        // jnp.round == round-half-to-even -> __float2int_rn
        int i0 = __float2int_rn(1000.0f * v.x) * 1024 + __float2int_rn(1000.0f * v.y);
        int i1 = __float2int_rn(1000.0f * v.z) * 1024 + __float2int_rn(1000.0f * v.w);
        uint32_t r0 = (uint32_t)i0 >> 14, b0 = (uint32_t)i0 & 16383u;
        uint32_t r1 = (uint32_t)i1 >> 14, b1 = (uint32_t)i1 & 16383u;
        uint32_t p0 = atomicAdd(&s_off[r0], 1u);
        if (p0 < (uint32_t)kSlots) s_stage[r0 * kStride + p0] = (uint16_t)b0;
        uint32_t p1 = atomicAdd(&s_off[r1], 1u);
        if (p1 < (uint32_t)kSlots) s_stage[r1 * kStride + p1] = (uint16_t)b1;
    }
    __syncthreads();

    // Flush: 1024 uint4 tasks = (region r, chunk k of 8 slots). All stores
    // 16B-aligned, 256 B contiguous per region-slice; empty slots get 0xFFFF
    // selected in-register (stale LDS never escapes).
#pragma unroll
    for (int it = 0; it < 4; ++it) {
        int t = it * kThreads + tid;
        uint32_t r = (uint32_t)t >> 4;
        uint32_t k = (uint32_t)t & 15u;
        uint32_t c = s_off[r];
        if (c > (uint32_t)kSlots) c = (uint32_t)kSlots;
        const uint4 w = *(const uint4*)&s_stage[r * kStride + k * 8u];
        uint32_t slot = k * 8u;
        uint4 o;
        o.x = ((slot + 0 < c) ? (w.x & 0xFFFFu) : 0xFFFFu) |
              (((slot + 1 < c) ? (w.x >> 16)    : 0xFFFFu) << 16);
        o.y = ((slot + 2 < c) ? (w.y & 0xFFFFu) : 0xFFFFu) |
              (((slot + 3 < c) ? (w.y >> 16)    : 0xFFFFu) << 16);
        o.z = ((slot + 4 < c) ? (w.z & 0xFFFFu) : 0xFFFFu) |
              (((slot + 5 < c) ? (w.z >> 16)    : 0xFFFFu) << 16);
        o.w = ((slot + 6 < c) ? (w.w & 0xFFFFu) : 0xFFFFu) |
              (((slot + 7 < c) ? (w.w >> 16)    : 0xFFFFu) << 16);
        uint16_t* dst = bdata + ((size_t)(cloud * kRegions + r) * kBucketSlots
                                 + (uint32_t)batch * kSlots + slot);
        *(uint4*)dst = o;
    }
}

__global__ void __launch_bounds__(kThreads) region_hist_kernel(
    const uint16_t* __restrict__ bdata, uint32_t* __restrict__ parts) {
    // u16-packed counters: 16384 bins in 8192 u32 = 32 KB. A bin's count is
    // bounded by the bucket capacity (8192 < 65536): no overflow/carry ever.
    __shared__ uint32_t hist[8192];
    __shared__ uint32_t s_wsum[kThreads / 64];
    const int tid = threadIdx.x;
    const int bid = blockIdx.x;  // bucket = cloud*64 + region

    uint4* h4 = (uint4*)hist;
    for (int i = tid; i < 8192 / 4; i += kThreads) h4[i] = make_uint4(0, 0, 0, 0);
    __syncthreads();

    const uint4* src4 = (const uint4*)(bdata + (size_t)bid * kBucketSlots);
#pragma unroll
    for (int it = 0; it < 4; ++it) {          // 1024 uint4 = fixed 16 KB
        uint4 v = src4[it * kThreads + tid];
        uint32_t w;
        w = v.x & 0xFFFFu; if (w < 16384u) atomicAdd(&hist[w >> 1], 1u << (16u * (w & 1u)));
        w = v.x >> 16;     if (w < 16384u) atomicAdd(&hist[w >> 1], 1u << (16u * (w & 1u)));
        w = v.y & 0xFFFFu; if (w < 16384u) atomicAdd(&hist[w >> 1], 1u << (16u * (w & 1u)));
        w = v.y >> 16;     if (w < 16384u) atomicAdd(&hist[w >> 1], 1u << (16u * (w & 1u)));
        w = v.z & 0xFFFFu; if (w < 16384u) atomicAdd(&hist[w >> 1], 1u << (16u * (w & 1u)));
        w = v.z >> 16;     if (w < 16384u) atomicAdd(&hist[w >> 1], 1u << (16u * (w & 1u)));
        w = v.w & 0xFFFFu; if (w < 16384u) atomicAdd(&hist[w >> 1], 1u << (16u * (w & 1u)));
        w = v.w >> 16;     if (w < 16384u) atomicAdd(&hist[w >> 1], 1u << (16u * (w & 1u)));
    }
    __syncthreads();

    uint32_t local = 0;
    for (int i = tid; i < 8192 / 4; i += kThreads) {
        uint4 v = h4[i];
        local += ((v.x & 0xFFFFu) >= kThresh) + ((v.x >> 16) >= kThresh);
        local += ((v.y & 0xFFFFu) >= kThresh) + ((v.y >> 16) >= kThresh);
        local += ((v.z & 0xFFFFu) >= kThresh) + ((v.z >> 16) >= kThresh);
        local += ((v.w & 0xFFFFu) >= kThresh) + ((v.w >> 16) >= kThresh);
    }
#pragma unroll
    for (int d = 32; d; d >>= 1) local += __shfl_down(local, d, 64);
    if ((tid & 63) == 0) s_wsum[tid >> 6] = local;
    __syncthreads();
    if (tid == 0)
        parts[bid] = s_wsum[0] + s_wsum[1] + s_wsum[2] + s_wsum[3];  // plain store
}

__global__ void __launch_bounds__(kThreads) out_kernel(const uint32_t* __restrict__ parts,
                                                       float* __restrict__ out) {
    __shared__ uint32_t s_m;
    const int b = blockIdx.x;  // one block per cloud
    const int tid = threadIdx.x;
    if (tid < 64) {
        uint32_t v = parts[b * kRegions + tid];
#pragma unroll
        for (int d = 32; d; d >>= 1) v += __shfl_down(v, d, 64);
        if (tid == 0) s_m = v;
    }
    __syncthreads();
    const uint32_t m = s_m;
    const uint32_t cut = m < (uint32_t)kTopK ? m : (uint32_t)kTopK;
    float4* row = (float4*)(out + (size_t)b * kTopK);
    for (int i = tid; i < kTopK / 4; i += kThreads) {
        uint32_t j = (uint32_t)i * 4u;
        row[i] = make_float4(j < cut ? 1.0f : 0.0f, j + 1 < cut ? 1.0f : 0.0f,
                             j + 2 < cut ? 1.0f : 0.0f, j + 3 < cut ? 1.0f : 0.0f);
    }
}

extern "C" void kernel_launch(void* const* d_in, const int* in_sizes, int n_in,
                              void* d_out, int out_size, void* d_ws, size_t ws_size,
                              hipStream_t stream) {
    const float4* pcd4 = (const float4*)d_in[0];
    float* out = (float*)d_out;

    uint32_t* parts = (uint32_t*)d_ws;
    uint16_t* bdata = (uint16_t*)((char*)d_ws + (1 << 20));

    // No memset: every consumed byte (bdata slices incl. sentinels, parts) is
    // written unconditionally each call before being read.

    bucketize_kernel<<<kB * kBlocksPerCloud, kThreads, 0, stream>>>(pcd4, bdata);
    region_hist_kernel<<<kB * kRegions, kThreads, 0, stream>>>(bdata, parts);
    out_kernel<<<kB, kThreads, 0, stream>>>(parts, out);
}